// Round 7
// baseline (59.070 us; speedup 1.0000x reference)
//
#include <hip/hip_runtime.h>
#include <math.h>

#define TS 49
#define LOG49 3.8918202981106265f
#define LN2 0.6931471805599453f

typedef short bf16x8 __attribute__((ext_vector_type(8)));  // 8 bf16 = 4 VGPRs
typedef float f32x4 __attribute__((ext_vector_type(4)));

// ws layout:
//   bytes [0, 8192): B-fragments bf16[nt=4][h=2][lane=64][s=8]
//     value = exp(trans[j][k]-Tmax), j = 4*(lane&15)+nt (state-out position),
//     k = 32*h + 8*(lane>>4) + s (state-in position); zero outside 49x49.
//   byte 8192: float Tmax

__global__ void prep_kernel(const float* __restrict__ tf, const float* __restrict__ w2,
                            const float* __restrict__ b2, float* __restrict__ ws) {
    __shared__ float tr[TS * TS];
    __shared__ float red[256];
    const int tid = threadIdx.x;
    const float w0 = w2[0], w1 = w2[1], w2v = w2[2], w3 = w2[3], w4 = w2[4], w5 = w2[5];
    const float bb = b2[0];
    float lmax = -INFINITY;
    for (int idx = tid; idx < TS * TS; idx += 256) {
        const float* p = tf + idx * 6;
        float s = bb + p[0]*w0 + p[1]*w1 + p[2]*w2v + p[3]*w3 + p[4]*w4 + p[5]*w5;
        tr[idx] = s;
        lmax = fmaxf(lmax, s);
    }
    red[tid] = lmax;
    __syncthreads();
    for (int s = 128; s > 0; s >>= 1) {
        if (tid < s) red[tid] = fmaxf(red[tid], red[tid + s]);
        __syncthreads();
    }
    const float Tmax = red[0];
    __syncthreads();
    unsigned short* B = (unsigned short*)ws;
    for (int idx = tid; idx < 4096; idx += 256) {
        const int s  = idx & 7;
        const int l  = (idx >> 3) & 63;
        const int h  = (idx >> 9) & 1;
        const int nt = idx >> 10;
        const int j = 4 * (l & 15) + nt;
        const int k = 32 * h + 8 * (l >> 4) + s;
        float v = (j < TS && k < TS) ? __expf(tr[j * TS + k] - Tmax) : 0.0f;
        unsigned bts = __float_as_uint(v);
        B[idx] = (unsigned short)((bts + 0x7FFFu + ((bts >> 16) & 1u)) >> 16);  // rne bf16
    }
    if (tid == 0) ((float*)ws)[2048] = Tmax;  // byte 8192
}

__device__ __forceinline__ unsigned cvtpk_bf16(float lo, float hi) {
    unsigned d;  // D[15:0] = bf16(lo), D[31:16] = bf16(hi)
    asm("v_cvt_pk_bf16_f32 %0, %1, %2" : "=v"(d) : "v"(lo), "v"(hi));
    return d;
}

// One wave = 16 chains. v[nt][t]: chain = 4*(l>>4)+t, state position p = 4*(l&15)+nt.
// V16: chain-major [16][64 bf16] with XOR swizzle for conflict-free b128 A-reads.
// EB: emission staging [2 slots][16 chains][64 floats]; value for position p stored
// at col p (col p holds orig emission col (p+48)%49: shift-by-1 with col48 dup at 0).
__global__ __launch_bounds__(64) void crf_fwd(const float* __restrict__ emis,
                                              const unsigned short* __restrict__ wsB,
                                              float* __restrict__ out, int L) {
    __shared__ __align__(16) unsigned short V16[1024];  // 2 KB
    __shared__ __align__(16) float EB[2][16][64];       // 8 KB
    const int l = threadIdx.x, g = l >> 4, c0 = l & 15;
    const int b0 = blockIdx.x * 16;
    const float Tmax = ((const float*)wsB)[2048];
    float* const EBf = (float*)EB;

    // zero EB once (cols >= 50 stay 0 forever; exp(0)=1 is annihilated by zero B-cols)
    {
        f32x4* z = (f32x4*)EB;
        f32x4 zz = {0.f, 0.f, 0.f, 0.f};
        #pragma unroll
        for (int q = 0; q < 8; ++q) z[q * 64 + l] = zz;
    }

    // B fragments, register-resident
    bf16x8 Bf[4][2];
    {
        const bf16x8* Bt = (const bf16x8*)wsB;
        #pragma unroll
        for (int nt = 0; nt < 4; ++nt)
            #pragma unroll
            for (int h = 0; h < 2; ++h) Bf[nt][h] = Bt[(nt * 2 + h) * 64 + l];
    }

    // V16 indices (as R6)
    int wi[4];
    #pragma unroll
    for (int t = 0; t < 4; ++t) {
        const int ch = 4 * g + t;
        wi[t] = ch * 16 + (c0 ^ ((ch & 7) << 1));
    }
    const int ra0 = c0 * 8 + (g ^ (c0 & 7));
    const int ra1 = c0 * 8 + ((4 + g) ^ (c0 & 7));
    uint2* const Vw = (uint2*)V16;
    const bf16x8* const Vr = (const bf16x8*)V16;

    // staging plan: 832 = 16 chains x 52 = 13 dwords/lane, coalesced
    const int LT = L * TS;
    unsigned off32[13];
    int ldsw[13];
    bool dup[13];
    #pragma unroll
    for (int q = 0; q < 13; ++q) {
        const int idx = 64 * q + l;
        const int ch = idx / 52, pos = idx - ch * 52;
        const bool active = pos <= 48;
        off32[q] = active ? (unsigned)((b0 + ch) * LT + pos) : 0u;
        ldsw[q]  = active ? (ch * 64 + pos + 1) : -1;
        dup[q]   = (pos == 48);  // orig col 48 also serves position 0
    }

    // consumption indices: float4 per t -> positions 4*c0..4*c0+3 of chain 4g+t
    int rdix[4];
    #pragma unroll
    for (int t = 0; t < 4; ++t) rdix[t] = 64 * g + 16 * t + c0;
    const f32x4* const EB4 = (const f32x4*)EB;  // slot stride = 256 f32x4

#define LOADQ(STEP) do {                                                              \
    const unsigned o = (unsigned)((STEP) * TS);                                       \
    _Pragma("unroll")                                                                 \
    for (int q = 0; q < 13; ++q) gl[q] = emis[off32[q] + o];                          \
} while (0)

#define WRITEQ(STEP) do {                                                             \
    const int sb = (((STEP) & 1) << 10);                                              \
    _Pragma("unroll")                                                                 \
    for (int q = 0; q < 13; ++q) {                                                    \
        if (ldsw[q] >= 0) {                                                           \
            EBf[sb + ldsw[q]] = gl[q];                                                \
            if (dup[q]) EBf[sb + ldsw[q] - 49] = gl[q];                               \
        }                                                                             \
    }                                                                                 \
} while (0)

    float gl[13];
    // prologue: fill slots for steps 0,1,2; hold step-3 loads in regs
    LOADQ(0); WRITEQ(0);
    LOADQ(1); WRITEQ(1);
    asm volatile("" ::: "memory");

    float v[4][4];
    #pragma unroll
    for (int t = 0; t < 4; ++t) {
        const f32x4 e4 = EB4[rdix[t]];  // slot 0 = step 0
        #pragma unroll
        for (int nt = 0; nt < 4; ++nt) {
            const bool live = (4 * c0 + nt) < TS;
            v[nt][t] = live ? __expf(e4[nt]) : 0.0f;
        }
    }
    asm volatile("" ::: "memory");
    if (L > 2) { LOADQ(2); WRITEQ(2); }
    if (L > 3) LOADQ(3);

    float sc[4]   = {0.f, 0.f, 0.f, 0.f};
    float fac[4]  = {1.f, 1.f, 1.f, 1.f};
    float pend[4] = {0.f, 0.f, 0.f, 0.f};

#define STEP(I, DO_COMPUTE, DO_APPLY) do {                                            \
    /* 1: pack v -> bf16, 4 x ds_write_b64 (swizzled) */                              \
    _Pragma("unroll")                                                                 \
    for (int t = 0; t < 4; ++t) {                                                     \
        uint2 u;                                                                      \
        u.x = cvtpk_bf16(v[0][t], v[1][t]);                                           \
        u.y = cvtpk_bf16(v[2][t], v[3][t]);                                           \
        Vw[wi[t]] = u;                                                                \
    }                                                                                 \
    /* 2: this step's emissions from LDS (written 2+ steps ago) */                    \
    const int sb = (((I) & 1) << 8);  /* f32x4 slot base */                           \
    f32x4 e4[4];                                                                      \
    _Pragma("unroll")                                                                 \
    for (int t = 0; t < 4; ++t) e4[t] = EB4[sb + rdix[t]];                            \
    asm volatile("" ::: "memory");                                                    \
    /* 3: commit reg-held step I+2 emissions to LDS (same slot, after reads) */       \
    if ((I) + 2 < L) WRITEQ((I) + 2);                                                 \
    /* 4: issue coalesced loads for step I+3 */                                       \
    if ((I) + 3 < L) LOADQ((I) + 3);                                                  \
    /* 5: ee */                                                                       \
    f32x4 ee[4];                                                                      \
    _Pragma("unroll")                                                                 \
    for (int t = 0; t < 4; ++t)                                                       \
        _Pragma("unroll")                                                             \
        for (int nt = 0; nt < 4; ++nt) ee[t][nt] = __expf(e4[t][nt]);                 \
    asm volatile("" ::: "memory");                                                    \
    /* 6: A-fragments (conflict-free b128) + MFMA + multiply */                       \
    const bf16x8 A0 = Vr[ra0];                                                        \
    const bf16x8 A1 = Vr[ra1];                                                        \
    _Pragma("unroll")                                                                 \
    for (int nt = 0; nt < 4; ++nt) {                                                  \
        f32x4 acc = {0.f, 0.f, 0.f, 0.f};                                             \
        acc = __builtin_amdgcn_mfma_f32_16x16x32_bf16(A0, Bf[nt][0], acc, 0, 0, 0);   \
        acc = __builtin_amdgcn_mfma_f32_16x16x32_bf16(A1, Bf[nt][1], acc, 0, 0, 0);   \
        _Pragma("unroll")                                                             \
        for (int t = 0; t < 4; ++t) {                                                 \
            float nv = acc[t] * ee[t][nt];                                            \
            if (DO_APPLY) nv *= fac[t];                                               \
            v[nt][t] = nv;                                                            \
        }                                                                             \
    }                                                                                 \
    if (DO_APPLY) {                                                                   \
        _Pragma("unroll")                                                             \
        for (int t = 0; t < 4; ++t) sc[t] += pend[t];                                 \
    }                                                                                 \
    /* 7: deferred renorm factor (one full step of slack before use) */               \
    if (DO_COMPUTE) {                                                                 \
        _Pragma("unroll")                                                             \
        for (int t = 0; t < 4; ++t) {                                                 \
            float mx = fmaxf(fmaxf(v[0][t], v[1][t]), fmaxf(v[2][t], v[3][t]));       \
            mx = fmaxf(mx, __shfl_xor(mx, 1, 64));                                    \
            mx = fmaxf(mx, __shfl_xor(mx, 2, 64));                                    \
            mx = fmaxf(mx, __shfl_xor(mx, 4, 64));                                    \
            mx = fmaxf(mx, __shfl_xor(mx, 8, 64));                                    \
            const unsigned ex = __float_as_uint(mx) >> 23;                            \
            fac[t]  = __uint_as_float((254u - ex) << 23);                             \
            pend[t] = (float)((int)ex - 127) * LN2;                                   \
        }                                                                             \
    }                                                                                 \
} while (0)

    int i = 1;
    for (; i + 1 < L; i += 2) {
        STEP(i, 1, 0);      // odd: compute renorm factor
        STEP(i + 1, 0, 1);  // even: apply it
    }
    if (i < L) STEP(i, 0, 0);  // tail
#undef STEP
#undef LOADQ
#undef WRITEQ

    // final: alpha[chain] = sc + log(sum_p V) + log49 + (L-1)*Tmax
    float res[4];
    #pragma unroll
    for (int t = 0; t < 4; ++t) {
        float s = (v[0][t] + v[1][t]) + (v[2][t] + v[3][t]);
        s += __shfl_xor(s, 1, 64);
        s += __shfl_xor(s, 2, 64);
        s += __shfl_xor(s, 4, 64);
        s += __shfl_xor(s, 8, 64);
        res[t] = sc[t] + __logf(s) + LOG49 + (float)(L - 1) * Tmax;
    }
    if (c0 == 0) {
        #pragma unroll
        for (int t = 0; t < 4; ++t) out[b0 + 4 * g + t] = res[t];
    }
}

extern "C" void kernel_launch(void* const* d_in, const int* in_sizes, int n_in,
                              void* d_out, int out_size, void* d_ws, size_t ws_size,
                              hipStream_t stream) {
    const float* emis = (const float*)d_in[0];
    const float* tf   = (const float*)d_in[1];
    const float* w2   = (const float*)d_in[2];
    const float* b2   = (const float*)d_in[3];
    float* out = (float*)d_out;
    float* ws  = (float*)d_ws;

    const int B = out_size;                // 8192
    const int L = in_sizes[0] / (B * TS);  // 48

    prep_kernel<<<1, 256, 0, stream>>>(tf, w2, b2, ws);
    crf_fwd<<<B / 16, 64, 0, stream>>>(emis, (const unsigned short*)ws, out, L);
}

// Round 8
// 37.323 us; speedup vs baseline: 1.5826x; 1.5826x over previous
//
#include <hip/hip_runtime.h>
#include <math.h>

#define TS 49
#define LOG49 3.8918202981106265f
#define LN2 0.6931471805599453f

typedef short bf16x8 __attribute__((ext_vector_type(8)));  // 8 bf16 = 4 VGPRs
typedef float f32x4 __attribute__((ext_vector_type(4)));
typedef float f32x4u __attribute__((ext_vector_type(4), aligned(4)));

// State relabeling: position p holds original state (p+1)%49, so position p's
// emission column is exactly p (the roll disappears; it is absorbed into B).
// ws layout:
//   bytes [0, 8192): B-fragments bf16[nt=4][h=2][lane=64][s=8]
//     value = exp(trans[(jp+1)%49][(kp+1)%49] - Tmax), jp = 4*(lane&15)+nt (out pos),
//     kp = 32*h + 8*(lane>>4) + s (in pos); zero outside jp<49 && kp<49.
//   byte 8192: float Tmax

__global__ void prep_kernel(const float* __restrict__ tf, const float* __restrict__ w2,
                            const float* __restrict__ b2, float* __restrict__ ws) {
    __shared__ float tr[TS * TS];
    __shared__ float red[256];
    const int tid = threadIdx.x;
    const float w0 = w2[0], w1 = w2[1], w2v = w2[2], w3 = w2[3], w4 = w2[4], w5 = w2[5];
    const float bb = b2[0];
    float lmax = -INFINITY;
    for (int idx = tid; idx < TS * TS; idx += 256) {
        const float* p = tf + idx * 6;
        float s = bb + p[0]*w0 + p[1]*w1 + p[2]*w2v + p[3]*w3 + p[4]*w4 + p[5]*w5;
        tr[idx] = s;
        lmax = fmaxf(lmax, s);
    }
    red[tid] = lmax;
    __syncthreads();
    for (int s = 128; s > 0; s >>= 1) {
        if (tid < s) red[tid] = fmaxf(red[tid], red[tid + s]);
        __syncthreads();
    }
    const float Tmax = red[0];
    __syncthreads();
    unsigned short* B = (unsigned short*)ws;
    for (int idx = tid; idx < 4096; idx += 256) {
        const int s  = idx & 7;
        const int l  = (idx >> 3) & 63;
        const int h  = (idx >> 9) & 1;
        const int nt = idx >> 10;
        const int jp = 4 * (l & 15) + nt;
        const int kp = 32 * h + 8 * (l >> 4) + s;
        float v = 0.0f;
        if (jp < TS && kp < TS) {
            const int jj = (jp + 1) % TS, kk = (kp + 1) % TS;
            v = __expf(tr[jj * TS + kk] - Tmax);
        }
        unsigned bts = __float_as_uint(v);
        B[idx] = (unsigned short)((bts + 0x7FFFu + ((bts >> 16) & 1u)) >> 16);  // rne bf16
    }
    if (tid == 0) ((float*)ws)[2048] = Tmax;  // byte 8192
}

__device__ __forceinline__ unsigned cvtpk_bf16(float lo, float hi) {
    unsigned d;  // D[15:0] = bf16(lo), D[31:16] = bf16(hi)
    asm("v_cvt_pk_bf16_f32 %0, %1, %2" : "=v"(d) : "v"(lo), "v"(hi));
    return d;
}

// One wave = 16 chains. v[nt][t]: chain = 4*(l>>4)+t, position p = 4*(l&15)+nt.
// V16: chain-major [16][64 bf16], XOR-swizzled for conflict-free b128 A-reads.
__global__ __launch_bounds__(64) void crf_fwd(const float* __restrict__ emis,
                                              const unsigned short* __restrict__ wsB,
                                              float* __restrict__ out, int L) {
    __shared__ __align__(16) unsigned short V16[1024];
    const int l = threadIdx.x, g = l >> 4, c0 = l & 15;
    const int b0 = blockIdx.x * 16;
    const float Tmax = ((const float*)wsB)[2048];

    // B fragments, register-resident
    bf16x8 Bf[4][2];
    {
        const bf16x8* Bt = (const bf16x8*)wsB;
        #pragma unroll
        for (int nt = 0; nt < 4; ++nt)
            #pragma unroll
            for (int h = 0; h < 2; ++h) Bf[nt][h] = Bt[(nt * 2 + h) * 64 + l];
    }

    // V16 LDS indices (validated in R6)
    int wi[4];
    #pragma unroll
    for (int t = 0; t < 4; ++t) {
        const int ch = 4 * g + t;
        wi[t] = ch * 16 + (c0 ^ ((ch & 7) << 1));  // uint2 units
    }
    const int ra0 = c0 * 8 + (g ^ (c0 & 7));        // bf16x8 units, k 0..31
    const int ra1 = c0 * 8 + ((4 + g) ^ (c0 & 7));  // k 32..63
    uint2* const Vw = (uint2*)V16;
    const bf16x8* const Vr = (const bf16x8*)V16;

    // Emission addressing: positions 4c0..4c0+3 = cols 4c0..4c0+3 (aligned x4).
    // Edge lanes (c0>=12) load cols 45..48: elem 3 = col 48 serves p=48 (c0==12,nt=0);
    // other elems are in-bounds garbage feeding dead positions (zero B rows).
    const int LT = L * TS;
    const bool sel12 = (c0 >= 12);
    const int col4 = sel12 ? 45 : 4 * c0;
    const float* ebase[4];
    #pragma unroll
    for (int t = 0; t < 4; ++t)
        ebase[t] = emis + (size_t)(b0 + 4 * g + t) * LT + col4;

    f32x4 pf[4][4];  // [slot][t], statically indexed only

#define LQ(STEP, SLOT) do {                                                           \
    _Pragma("unroll")                                                                 \
    for (int t = 0; t < 4; ++t)                                                       \
        pf[SLOT][t] = *(const f32x4u*)(ebase[t] + (STEP) * TS);                       \
} while (0)

#define EESEL(DST, SLOT) do {                                                         \
    _Pragma("unroll")                                                                 \
    for (int t = 0; t < 4; ++t) {                                                     \
        const f32x4 q = pf[SLOT][t];                                                  \
        DST[0][t] = __expf(sel12 ? q.w : q.x);                                        \
        DST[1][t] = __expf(q.y);                                                      \
        DST[2][t] = __expf(q.z);                                                      \
        DST[3][t] = __expf(q.w);                                                      \
    }                                                                                 \
} while (0)

    // prologue: fill 4 slots
    LQ(0, 0);
    if (L > 1) LQ(1, 1);
    if (L > 2) LQ(2, 2);
    if (L > 3) LQ(3, 3);

    // init V_0 from slot 0: v = exp(emit[0][p]), dead positions -> 0
    float v[4][4];
    #pragma unroll
    for (int t = 0; t < 4; ++t) {
        const f32x4 q = pf[0][t];
        const float i0 = sel12 ? q.w : q.x;
        v[0][t] = (4 * c0 + 0 < TS) ? __expf(i0)  : 0.0f;
        v[1][t] = (4 * c0 + 1 < TS) ? __expf(q.y) : 0.0f;
        v[2][t] = (4 * c0 + 2 < TS) ? __expf(q.z) : 0.0f;
        v[3][t] = (4 * c0 + 3 < TS) ? __expf(q.w) : 0.0f;
    }

    float ee0[4][4], ee1[4][4];
    EESEL(ee1, 1);  // emissions for step 1

    float sc[4]   = {0.f, 0.f, 0.f, 0.f};
    float fac[4]  = {1.f, 1.f, 1.f, 1.f};
    float pend[4] = {0.f, 0.f, 0.f, 0.f};

#define STEP(I, EC, EN, SN, SL, DO_C, DO_A) do {                                      \
    /* 1: pack v -> bf16, 4 x ds_write_b64 (swizzled) */                              \
    _Pragma("unroll")                                                                 \
    for (int t = 0; t < 4; ++t) {                                                     \
        uint2 u;                                                                      \
        u.x = cvtpk_bf16(v[0][t], v[1][t]);                                           \
        u.y = cvtpk_bf16(v[2][t], v[3][t]);                                           \
        Vw[wi[t]] = u;                                                                \
    }                                                                                 \
    /* 2: next step's ee (pads DS drain; loads landed >=3 steps ago) */               \
    EESEL(EN, SN);                                                                    \
    /* 3: issue loads for step I+3 */                                                 \
    if ((I) + 3 < L) LQ((I) + 3, SL);                                                 \
    asm volatile("" ::: "memory");                                                    \
    /* 4: A-fragments (conflict-free b128; same-wave DS in-order) */                  \
    const bf16x8 A0 = Vr[ra0];                                                        \
    const bf16x8 A1 = Vr[ra1];                                                        \
    /* 5+6: MFMA + emission/renorm multiply */                                        \
    _Pragma("unroll")                                                                 \
    for (int nt = 0; nt < 4; ++nt) {                                                  \
        f32x4 acc = {0.f, 0.f, 0.f, 0.f};                                             \
        acc = __builtin_amdgcn_mfma_f32_16x16x32_bf16(A0, Bf[nt][0], acc, 0, 0, 0);   \
        acc = __builtin_amdgcn_mfma_f32_16x16x32_bf16(A1, Bf[nt][1], acc, 0, 0, 0);   \
        _Pragma("unroll")                                                             \
        for (int t = 0; t < 4; ++t) {                                                 \
            float nv = acc[t] * EC[nt][t];                                            \
            if (DO_A) nv *= fac[t];                                                   \
            v[nt][t] = nv;                                                            \
        }                                                                             \
    }                                                                                 \
    if (DO_A) {                                                                       \
        _Pragma("unroll")                                                             \
        for (int t = 0; t < 4; ++t) sc[t] += pend[t];                                 \
    }                                                                                 \
    /* 7: renorm factor (applied next step; shfl chain off critical path) */          \
    if (DO_C) {                                                                       \
        _Pragma("unroll")                                                             \
        for (int t = 0; t < 4; ++t) {                                                 \
            float mx = fmaxf(fmaxf(v[0][t], v[1][t]), fmaxf(v[2][t], v[3][t]));       \
            mx = fmaxf(mx, __shfl_xor(mx, 1, 64));                                    \
            mx = fmaxf(mx, __shfl_xor(mx, 2, 64));                                    \
            mx = fmaxf(mx, __shfl_xor(mx, 4, 64));                                    \
            mx = fmaxf(mx, __shfl_xor(mx, 8, 64));                                    \
            const unsigned ex = __float_as_uint(mx) >> 23;                            \
            fac[t]  = __uint_as_float((254u - ex) << 23);                             \
            pend[t] = (float)((int)ex - 127) * LN2;                                   \
        }                                                                             \
    }                                                                                 \
} while (0)

    const int S = L - 1;  // steps 1..S
    int i = 1;
    for (; i + 3 <= S; i += 4) {  // i = 1 mod 4 -> static pf slots
        STEP(i + 0, ee1, ee0, 2, 0, 1, 0);
        STEP(i + 1, ee0, ee1, 3, 1, 0, 1);
        STEP(i + 2, ee1, ee0, 0, 2, 0, 0);
        STEP(i + 3, ee0, ee1, 1, 3, 0, 0);
    }
    if (i <= S)     STEP(i,     ee1, ee0, 2, 0, 1, 0);
    if (i + 1 <= S) STEP(i + 1, ee0, ee1, 3, 1, 0, 1);
    if (i + 2 <= S) STEP(i + 2, ee1, ee0, 0, 2, 0, 0);
#undef STEP
#undef EESEL
#undef LQ

    // final: alpha[chain] = sc + log(sum_p V) + log49 + (L-1)*Tmax
    float res[4];
    #pragma unroll
    for (int t = 0; t < 4; ++t) {
        float s = (v[0][t] + v[1][t]) + (v[2][t] + v[3][t]);
        s += __shfl_xor(s, 1, 64);
        s += __shfl_xor(s, 2, 64);
        s += __shfl_xor(s, 4, 64);
        s += __shfl_xor(s, 8, 64);
        res[t] = sc[t] + __logf(s) + LOG49 + (float)(L - 1) * Tmax;
    }
    if (c0 == 0) {
        #pragma unroll
        for (int t = 0; t < 4; ++t) out[b0 + 4 * g + t] = res[t];
    }
}

extern "C" void kernel_launch(void* const* d_in, const int* in_sizes, int n_in,
                              void* d_out, int out_size, void* d_ws, size_t ws_size,
                              hipStream_t stream) {
    const float* emis = (const float*)d_in[0];
    const float* tf   = (const float*)d_in[1];
    const float* w2   = (const float*)d_in[2];
    const float* b2   = (const float*)d_in[3];
    float* out = (float*)d_out;
    float* ws  = (float*)d_ws;

    const int B = out_size;                // 8192
    const int L = in_sizes[0] / (B * TS);  // 48

    prep_kernel<<<1, 256, 0, stream>>>(tf, w2, b2, ws);
    crf_fwd<<<B / 16, 64, 0, stream>>>(emis, (const unsigned short*)ws, out, L);
}